// Round 5
// baseline (137.600 us; speedup 1.0000x reference)
//
#include <hip/hip_runtime.h>

// similarity[r] = sum_a (pp[r,a] - ph[a])^2, a in [0,32); output = min_r similarity[r]
// pp: [R, 32] fp32 row-major, ph: [32] fp32, out: 1 fp32 scalar.
//
// Round-5: single fused kernel + one 384 B memset node.
//  - Stage identical to round 4 (coalesced float4 x8 per thread -> padded LDS
//    transpose -> lane-local row compute): measured ~5.9 TB/s, near read ceiling.
//  - Partial mins: atomicMin(uint) spread over 64 slots (64 distinct lines) ->
//    ~61 RMWs per line, hidden under the stream (vs 23 us for 1 contended line).
//  - Ticket counter (acq_rel, agent scope): the last block to finish reduces
//    the 64 slots (~0.3 us) and writes d_out. No second reduce kernel.
//  - memset(0x7F) initializes counter AND slots: 0x7F7F7F7F as float = 3.4e38
//    (acts as +inf; uint order == float order for non-negative floats), and
//    the counter's last ticket is 0x7F7F7F7F + grid - 1, deterministic per call.

#define INIT_PATTERN 0x7F7F7F7Fu

__global__ __launch_bounds__(256) void doa_fused_kernel(
    const float* __restrict__ pp,
    const float* __restrict__ ph,
    unsigned int* __restrict__ ws,   // [0]: ticket counter; [16..80): 64 min slots
    float* __restrict__ out,
    int R,
    unsigned int last_ticket)
{
    __shared__ float4 lds[256 * 9];   // 36 KB: 256 rows x (8 data + 1 pad) float4

    const int t = threadIdx.x;
    const long long base_row = (long long)blockIdx.x * 256;

    // phases: wave-uniform -> SGPRs
    float q[32];
#pragma unroll
    for (int a = 0; a < 32; ++a) q[a] = ph[a];

    // Stage 1: 8 independent coalesced float4 loads per thread (8 KB/wave in flight)
    const float4* src = reinterpret_cast<const float4*>(pp);
    const long long gmax = (long long)R * 8;
    float4 v[8];
#pragma unroll
    for (int i = 0; i < 8; ++i) {
        long long g = base_row * 8 + i * 256 + t;
        if (g >= gmax) g = 0;          // clamp; value unused for r >= R
        v[i] = src[g];
    }
#pragma unroll
    for (int i = 0; i < 8; ++i) {
        const int idx = i * 256 + t;   // float4 index within block's 256 rows
        lds[(idx >> 3) * 9 + (idx & 7)] = v[i];   // padded stride: conflict-free
    }
    __syncthreads();

    // Stage 2: each lane computes its own row from LDS (no shuffles in data path)
    float s = __builtin_inff();
    if (base_row + t < R) {
        s = 0.0f;
#pragma unroll
        for (int k = 0; k < 8; ++k) {
            const float4 p = lds[t * 9 + k];
            const float dx = p.x - q[4 * k + 0];
            const float dy = p.y - q[4 * k + 1];
            const float dz = p.z - q[4 * k + 2];
            const float dw = p.w - q[4 * k + 3];
            s += dx * dx + dy * dy + dz * dz + dw * dw;
        }
    }

    // one wave-wide min butterfly per wave lifetime
#pragma unroll
    for (int off = 1; off < 64; off <<= 1)
        s = fminf(s, __shfl_xor(s, off));

    __shared__ float wmin[4];
    __shared__ bool amLast;
    const int lane = t & 63;
    const int wid  = t >> 6;
    if (lane == 0) wmin[wid] = s;
    __syncthreads();
    if (t == 0) {
        const float m = fminf(fminf(wmin[0], wmin[1]), fminf(wmin[2], wmin[3]));
        // spread contention across 64 distinct cachelines; uint min == float min (m >= 0)
        atomicMin(&ws[16 + (blockIdx.x & 63)], __float_as_uint(m));
        // ticket: acq_rel release-sequence makes every block's slot-RMW visible
        // to the acquirer of the final ticket
        const unsigned int prev = __hip_atomic_fetch_add(
            &ws[0], 1u, __ATOMIC_ACQ_REL, __HIP_MEMORY_SCOPE_AGENT);
        amLast = (prev == last_ticket);
    }
    __syncthreads();

    if (amLast) {
        // last block: reduce the 64 slots (wave 0 only) and write the output
        if (t < 64) {
            const unsigned int u = __hip_atomic_load(
                &ws[16 + t], __ATOMIC_RELAXED, __HIP_MEMORY_SCOPE_AGENT);
            float m = __uint_as_float(u);
#pragma unroll
            for (int off = 1; off < 64; off <<= 1)
                m = fminf(m, __shfl_xor(m, off));
            if (t == 0) *out = m;
        }
    }
}

extern "C" void kernel_launch(void* const* d_in, const int* in_sizes, int n_in,
                              void* d_out, int out_size, void* d_ws, size_t ws_size,
                              hipStream_t stream) {
    const float* pp = (const float*)d_in[0];   // possible_phases [R, 32]
    const float* ph = (const float*)d_in[1];   // phases [32]
    float* out = (float*)d_out;                // 1 fp32 scalar
    unsigned int* ws = (unsigned int*)d_ws;

    const int R = in_sizes[0] / 32;
    const int grid = (R + 255) / 256;          // 3907 blocks for R = 1e6

    // counter (ws[0]) = 0x7F7F7F7F, 64 slots (ws[16..80)) = 0x7F7F7F7F ~ +inf
    hipMemsetAsync(ws, 0x7F, 384, stream);

    const unsigned int last_ticket = INIT_PATTERN + (unsigned int)grid - 1u;
    doa_fused_kernel<<<grid, 256, 0, stream>>>(pp, ph, ws, out, R, last_ticket);
}

// Round 6
// 66.380 us; speedup vs baseline: 2.0729x; 2.0729x over previous
//
#include <hip/hip_runtime.h>

// similarity[r] = sum_a (pp[r,a] - ph[a])^2, a in [0,32); output = min_r similarity[r]
// pp: [R, 32] fp32 row-major, ph: [32] fp32, out: 1 fp32 scalar.
//
// Round-6: fused single-pass, ZERO ordering fences.
//  Round-5 post-mortem: ACQ_REL agent atomics emit buffer_wbl2/buffer_inv
//  (L2 writeback/invalidate) per block -> 3907 L2 nukes serialized the whole
//  kernel (215 us, 300 GB/s). Fix: relaxed-only atomics (no cache maintenance;
//  device-scope atomicMin proven coherent across XCDs in rounds 1-3) plus an
//  explicit `s_waitcnt vmcnt(0)` between the slot-min and the ticket add:
//  the min is performed at the coherence point before the ticket increments,
//  giving the needed happens-before in hardware.
//  - Stage identical to round 4: 8 coalesced float4 loads/thread -> padded
//    LDS transpose -> lane-local row compute (~5.9 TB/s, ~94% of read ceiling).
//  - Partial mins: relaxed atomicMin(uint) spread over 64 cachelines.
//  - Last ticket holder reduces the 64 slots and writes d_out (no 2nd kernel).
//  - 384 B memset(0x7F) re-inits counter+slots every call: counter starts at
//    0x7F7F7F7F (last ticket = 0x7F7F7F7F+grid-1), slots at 0x7F7F7F7F which
//    exceeds any finite sum-of-squares bit pattern we produce (<= ~0x449E...).

#define INIT_PATTERN 0x7F7F7F7Fu

__global__ __launch_bounds__(256) void doa_fused_kernel(
    const float* __restrict__ pp,
    const float* __restrict__ ph,
    unsigned int* __restrict__ ws,   // [0]: ticket counter; [16..80): 64 min slots
    float* __restrict__ out,
    int R,
    unsigned int last_ticket)
{
    __shared__ float4 lds[256 * 9];   // 36 KB: 256 rows x (8 data + 1 pad) float4

    const int t = threadIdx.x;
    const long long base_row = (long long)blockIdx.x * 256;

    // phases: wave-uniform -> SGPRs
    float q[32];
#pragma unroll
    for (int a = 0; a < 32; ++a) q[a] = ph[a];

    // Stage 1: 8 independent coalesced float4 loads per thread (8 KB/wave in flight)
    const float4* src = reinterpret_cast<const float4*>(pp);
    const long long gmax = (long long)R * 8;
    float4 v[8];
#pragma unroll
    for (int i = 0; i < 8; ++i) {
        long long g = base_row * 8 + i * 256 + t;
        if (g >= gmax) g = 0;          // clamp; value unused for r >= R
        v[i] = src[g];
    }
#pragma unroll
    for (int i = 0; i < 8; ++i) {
        const int idx = i * 256 + t;   // float4 index within block's 256 rows
        lds[(idx >> 3) * 9 + (idx & 7)] = v[i];   // padded stride: conflict-free
    }
    __syncthreads();

    // Stage 2: each lane computes its own row from LDS (no shuffles in data path)
    float s = __builtin_inff();
    if (base_row + t < R) {
        s = 0.0f;
#pragma unroll
        for (int k = 0; k < 8; ++k) {
            const float4 p = lds[t * 9 + k];
            const float dx = p.x - q[4 * k + 0];
            const float dy = p.y - q[4 * k + 1];
            const float dz = p.z - q[4 * k + 2];
            const float dw = p.w - q[4 * k + 3];
            s += dx * dx + dy * dy + dz * dz + dw * dw;
        }
    }

    // one wave-wide min butterfly per wave lifetime
#pragma unroll
    for (int off = 1; off < 64; off <<= 1)
        s = fminf(s, __shfl_xor(s, off));

    __shared__ float wmin[4];
    __shared__ bool amLast;
    const int lane = t & 63;
    const int wid  = t >> 6;
    if (lane == 0) wmin[wid] = s;
    __syncthreads();
    if (t == 0) {
        const float m = fminf(fminf(wmin[0], wmin[1]), fminf(wmin[2], wmin[3]));
        // relaxed device-scope RMW, spread over 64 distinct cachelines;
        // uint min == float min for non-negative floats
        atomicMin(&ws[16 + (blockIdx.x & 63)], __float_as_uint(m));
        // hardware happens-before WITHOUT acq/rel cache maintenance:
        // wait until the slot-min is performed at the coherence point,
        // only then publish our ticket.
        __asm__ volatile("s_waitcnt vmcnt(0)" ::: "memory");
        const unsigned int prev = __hip_atomic_fetch_add(
            &ws[0], 1u, __ATOMIC_RELAXED, __HIP_MEMORY_SCOPE_AGENT);
        amLast = (prev == last_ticket);
    }
    __syncthreads();

    // last block: every other block's slot-min completed before its ticket,
    // so relaxed atomic loads of the slots see the final values.
    if (amLast && t < 64) {
        const unsigned int u = __hip_atomic_load(
            &ws[16 + t], __ATOMIC_RELAXED, __HIP_MEMORY_SCOPE_AGENT);
        float m = __uint_as_float(u);
#pragma unroll
        for (int off = 1; off < 64; off <<= 1)
            m = fminf(m, __shfl_xor(m, off));
        if (t == 0) *out = m;
    }
}

extern "C" void kernel_launch(void* const* d_in, const int* in_sizes, int n_in,
                              void* d_out, int out_size, void* d_ws, size_t ws_size,
                              hipStream_t stream) {
    const float* pp = (const float*)d_in[0];   // possible_phases [R, 32]
    const float* ph = (const float*)d_in[1];   // phases [32]
    float* out = (float*)d_out;                // 1 fp32 scalar
    unsigned int* ws = (unsigned int*)d_ws;

    const int R = in_sizes[0] / 32;
    const int grid = (R + 255) / 256;          // 3907 blocks for R = 1e6

    // counter (ws[0]) = 0x7F7F7F7F, 64 slots (ws[16..80)) = 0x7F7F7F7F
    hipMemsetAsync(ws, 0x7F, 384, stream);

    const unsigned int last_ticket = INIT_PATTERN + (unsigned int)grid - 1u;
    doa_fused_kernel<<<grid, 256, 0, stream>>>(pp, ph, ws, out, R, last_ticket);
}

// Round 7
// 31.669 us; speedup vs baseline: 4.3449x; 2.0960x over previous
//
#include <hip/hip_runtime.h>

// similarity[r] = sum_a (pp[r,a] - ph[a])^2, a in [0,32); output = min_r similarity[r]
// pp: [R, 32] fp32 row-major, ph: [32] fp32, out: 1 fp32 scalar.
//
// Round-7: fused single-pass with FULLY-SPREAD relaxed atomics.
//  Lesson r1-r6: N same-cacheline device RMWs cost ~6 ns * N additively
//  (L2-line ownership bouncing across 8 XCDs), independent of ordering
//  semantics; ACQ_REL additionally nukes L2 (r5). So: relaxed-only, and
//  every RMW stream spread across lines.
//   - 64 min-slots at 128 B stride (1 per L2 line): ~61 RMWs/line, parallel.
//   - Completion via hierarchical counters: per-slot sub-counter on the same
//     line as its slot; the block that closes a slot's quota bumps the top
//     counter -> only 64 RMWs on the top line.
//   - Ordering: s_waitcnt vmcnt(0) between slot-min and sub-add (slot-min is
//     performed at the coherence point before the sub-add publishes);
//     RMW-return implies the sub-add is performed before the top-add.
//     Correctness of this fence-free pattern validated in r6 (absmax 0).
//   - Last closer reduces the 64 slots via relaxed agent atomic loads and
//     writes d_out. One 8.3 KB memset(0x7F) node re-inits per call:
//     slots = 0x7F7F7F7F (acts as +inf for non-negative floats, uint order
//     == float order); counters start at 0x7F7F7F7F -> quota compares offset.
//  Stage is byte-identical to round 4 (coalesced float4 x8 -> padded LDS
//  transpose -> lane-local row compute; measured ~5.9 TB/s, 94% of ceiling).

#define INIT_PATTERN 0x7F7F7F7Fu

// ws layout (uint indices): line s (s in [0,64)) at s*32: [0]=min slot,
// [1]=sub-counter. Top counter at 64*32 = 2048. Total 8196 B -> memset 8320.

__global__ __launch_bounds__(256) void doa_fused_kernel(
    const float* __restrict__ pp,
    const float* __restrict__ ph,
    unsigned int* __restrict__ ws,
    float* __restrict__ out,
    int R,
    int grid)
{
    __shared__ float4 lds[256 * 9];   // 36 KB: 256 rows x (8 data + 1 pad) float4

    const int t = threadIdx.x;
    const long long base_row = (long long)blockIdx.x * 256;

    // phases: wave-uniform -> SGPRs
    float q[32];
#pragma unroll
    for (int a = 0; a < 32; ++a) q[a] = ph[a];

    // Stage 1: 8 independent coalesced float4 loads per thread (8 KB/wave in flight)
    const float4* src = reinterpret_cast<const float4*>(pp);
    const long long gmax = (long long)R * 8;
    float4 v[8];
#pragma unroll
    for (int i = 0; i < 8; ++i) {
        long long g = base_row * 8 + i * 256 + t;
        if (g >= gmax) g = 0;          // clamp; value unused for r >= R
        v[i] = src[g];
    }
#pragma unroll
    for (int i = 0; i < 8; ++i) {
        const int idx = i * 256 + t;   // float4 index within block's 256 rows
        lds[(idx >> 3) * 9 + (idx & 7)] = v[i];   // padded stride: conflict-free
    }
    __syncthreads();

    // Stage 2: each lane computes its own row from LDS (no shuffles in data path)
    float s = __builtin_inff();
    if (base_row + t < R) {
        s = 0.0f;
#pragma unroll
        for (int k = 0; k < 8; ++k) {
            const float4 p = lds[t * 9 + k];
            const float dx = p.x - q[4 * k + 0];
            const float dy = p.y - q[4 * k + 1];
            const float dz = p.z - q[4 * k + 2];
            const float dw = p.w - q[4 * k + 3];
            s += dx * dx + dy * dy + dz * dz + dw * dw;
        }
    }

    // one wave-wide min butterfly per wave lifetime
#pragma unroll
    for (int off = 1; off < 64; off <<= 1)
        s = fminf(s, __shfl_xor(s, off));

    __shared__ float wmin[4];
    __shared__ bool amLast;
    const int lane = t & 63;
    const int wid  = t >> 6;
    if (lane == 0) wmin[wid] = s;
    __syncthreads();

    if (t == 0) {
        const float m = fminf(fminf(wmin[0], wmin[1]), fminf(wmin[2], wmin[3]));
        const int slot = blockIdx.x & 63;
        unsigned int* line = ws + slot * 32;     // 128 B stride: one L2 line per slot

        // (1) slot min: relaxed device RMW, ~61 per line, 64 lines in parallel
        __hip_atomic_fetch_min(&line[0], __float_as_uint(m),
                               __ATOMIC_RELAXED, __HIP_MEMORY_SCOPE_AGENT);
        // (2) make the slot-min performed at the coherence point, THEN publish
        __asm__ volatile("s_waitcnt vmcnt(0)" ::: "memory");
        const unsigned int sub_prev = __hip_atomic_fetch_add(
            &line[1], 1u, __ATOMIC_RELAXED, __HIP_MEMORY_SCOPE_AGENT);

        // (3) quota for this slot: blocks with bid%64==slot
        const unsigned int quota =
            (unsigned int)(grid >> 6) + ((slot < (grid & 63)) ? 1u : 0u);
        bool last = false;
        if (sub_prev == INIT_PATTERN + quota - 1u) {
            // this block closed its slot; only 64 RMWs ever hit the top line
            const unsigned int top_prev = __hip_atomic_fetch_add(
                &ws[64 * 32], 1u, __ATOMIC_RELAXED, __HIP_MEMORY_SCOPE_AGENT);
            last = (top_prev == INIT_PATTERN + 63u);
        }
        amLast = last;
    }
    __syncthreads();

    // last closer: all 64 slots are final; reduce and write the output
    if (amLast && t < 64) {
        const unsigned int u = __hip_atomic_load(
            &ws[t * 32], __ATOMIC_RELAXED, __HIP_MEMORY_SCOPE_AGENT);
        float m = __uint_as_float(u);
#pragma unroll
        for (int off = 1; off < 64; off <<= 1)
            m = fminf(m, __shfl_xor(m, off));
        if (t == 0) *out = m;
    }
}

extern "C" void kernel_launch(void* const* d_in, const int* in_sizes, int n_in,
                              void* d_out, int out_size, void* d_ws, size_t ws_size,
                              hipStream_t stream) {
    const float* pp = (const float*)d_in[0];   // possible_phases [R, 32]
    const float* ph = (const float*)d_in[1];   // phases [32]
    float* out = (float*)d_out;                // 1 fp32 scalar
    unsigned int* ws = (unsigned int*)d_ws;

    const int R = in_sizes[0] / 32;
    const int grid = (R + 255) / 256;          // 3907 blocks for R = 1e6

    // 64 lines (slot+sub-counter) + top counter: 8196 B -> clear 8320 B to 0x7F
    hipMemsetAsync(ws, 0x7F, 8320, stream);

    doa_fused_kernel<<<grid, 256, 0, stream>>>(pp, ph, ws, out, R, grid);
}

// Round 8
// 28.334 us; speedup vs baseline: 4.8563x; 1.1177x over previous
//
#include <hip/hip_runtime.h>

// similarity[r] = sum_a (pp[r,a] - ph[a])^2, a in [0,32); output = min_r similarity[r]
// pp: [R, 32] fp32 row-major, ph: [32] fp32, out: 1 fp32 scalar.
//
// Round-8: revert to round-4's two-node structure (plain-store partials +
// tiny reducer kernel) — r5-r7 proved any in-kernel cross-block combine
// exposes atomic round-trip latency in the block tail (+5 us), while plain
// stores are fire-and-forget. Two refinements vs round 4:
//  1. LDS 36 KB -> exactly 32 KB: XOR swizzle (k ^= row&7) instead of +1-pad
//     (same conflict-free banking on write and read; wmin aliased into lds
//     after a barrier) -> 5 resident blocks/CU instead of 4, +25% MLP.
//  2. Reducer 1024 -> 256 threads (latency-bound node; lighter dispatch).

__global__ __launch_bounds__(256) void doa_stage_kernel(
    const float* __restrict__ pp,
    const float* __restrict__ ph,
    float* __restrict__ ws,
    int R)
{
    __shared__ float4 lds[2048];   // exactly 32 KB -> 5 blocks/CU

    const int t = threadIdx.x;
    const long long base_row = (long long)blockIdx.x * 256;

    // phases: wave-uniform -> SGPRs
    float q[32];
#pragma unroll
    for (int a = 0; a < 32; ++a) q[a] = ph[a];

    // Stage 1: 8 independent coalesced float4 loads per thread (8 KB/wave in flight)
    const float4* src = reinterpret_cast<const float4*>(pp);
    const long long gmax = (long long)R * 8;
    float4 v[8];
#pragma unroll
    for (int i = 0; i < 8; ++i) {
        long long g = base_row * 8 + i * 256 + t;
        if (g >= gmax) g = 0;          // clamp; value unused for r >= R
        v[i] = src[g];
    }
    // XOR-swizzled store: slot = row*8 + (k ^ (row&7)).
    // Write: each wave covers 64 consecutive (permuted-within-row) slots ->
    // same banking as linear = conflict-free floor (8 cyc/b128-wave).
    // Read at fixed k: float4 addr t*8 + (k^(t&7)) -> bank group 4*(k^(t&7))
    // covers all 32 banks across the 8 lane-classes -> 8-cycle floor too.
#pragma unroll
    for (int i = 0; i < 8; ++i) {
        const int idx = i * 256 + t;   // float4 index within block's 256 rows
        const int row = idx >> 3;
        const int k   = idx & 7;
        lds[row * 8 + (k ^ (row & 7))] = v[i];
    }
    __syncthreads();

    // Stage 2: each lane computes its own row from LDS (no shuffles in data path)
    float s = __builtin_inff();
    if (base_row + t < R) {
        s = 0.0f;
#pragma unroll
        for (int k = 0; k < 8; ++k) {
            const float4 p = lds[t * 8 + (k ^ (t & 7))];
            const float dx = p.x - q[4 * k + 0];
            const float dy = p.y - q[4 * k + 1];
            const float dz = p.z - q[4 * k + 2];
            const float dw = p.w - q[4 * k + 3];
            s += dx * dx + dy * dy + dz * dz + dw * dw;
        }
    }

    // one wave-wide min butterfly per wave lifetime
#pragma unroll
    for (int off = 1; off < 64; off <<= 1)
        s = fminf(s, __shfl_xor(s, off));

    __syncthreads();               // all lds reads complete before aliasing
    float* wmin = reinterpret_cast<float*>(lds);   // reuse lds: keeps block at 32 KB
    if ((t & 63) == 0) wmin[t >> 6] = s;
    __syncthreads();
    if (t == 0) {
        // plain store: fire-and-forget, no atomic tail
        ws[blockIdx.x] = fminf(fminf(wmin[0], wmin[1]), fminf(wmin[2], wmin[3]));
    }
}

__global__ __launch_bounds__(256) void doa_reduce_kernel(
    const float* __restrict__ ws,
    float* __restrict__ out,
    int n)
{
    float s = __builtin_inff();
    for (int i = threadIdx.x; i < n; i += 256)
        s = fminf(s, ws[i]);

#pragma unroll
    for (int off = 1; off < 64; off <<= 1)
        s = fminf(s, __shfl_xor(s, off));

    __shared__ float wmin[4];
    if ((threadIdx.x & 63) == 0) wmin[threadIdx.x >> 6] = s;
    __syncthreads();
    if (threadIdx.x == 0)
        *out = fminf(fminf(wmin[0], wmin[1]), fminf(wmin[2], wmin[3]));
}

extern "C" void kernel_launch(void* const* d_in, const int* in_sizes, int n_in,
                              void* d_out, int out_size, void* d_ws, size_t ws_size,
                              hipStream_t stream) {
    const float* pp = (const float*)d_in[0];   // possible_phases [R, 32]
    const float* ph = (const float*)d_in[1];   // phases [32]
    float* out = (float*)d_out;                // 1 fp32 scalar
    float* ws  = (float*)d_ws;                 // per-block partial mins

    const int R = in_sizes[0] / 32;
    const int grid = (R + 255) / 256;          // 3907 blocks for R = 1e6

    doa_stage_kernel<<<grid, 256, 0, stream>>>(pp, ph, ws, R);
    doa_reduce_kernel<<<1, 256, 0, stream>>>(ws, out, grid);
}